// Round 1
// baseline (96.539 us; speedup 1.0000x reference)
//
#include <hip/hip_runtime.h>
#include <math.h>

// Problem constants (from reference): B=128, L_I=2, L_H=150, L_Q=10, IMSIZE=64, K=50
#define NB  128
#define IMS 64
#define NA  10
#define NH  150

// Key algebra: r = conv(h, r_w 1x1) where h = conv(X, h_w)+h_b  collapses to
//   r = conv(X, rw_comb) + rb,  rw_comb[c,ky,kx] = sum_h r_w[h]*h_w[h,c,ky,kx],
//   rb = sum_h r_w[h]*h_b[h].
// Key data fact (detected at runtime, NOT assumed): w (v-channel of w_cat) is all
// zeros -> every VI step gives q[a] = conv(r, q_w[a]) independent of v, so the
// final gather needs only a 3x3 patch of r around (S1,S2). General w != 0 falls
// back to a full in-LDS value iteration (correct for any inputs / any k).

__global__ __launch_bounds__(256) void vin_all(
    const float* __restrict__ X,
    const float* __restrict__ h_w,
    const float* __restrict__ h_b,
    const float* __restrict__ r_w,
    const float* __restrict__ q_w,
    const float* __restrict__ w,
    const float* __restrict__ fc_w,
    const int*   __restrict__ S1,
    const int*   __restrict__ S2,
    const int*   __restrict__ kptr,
    float*       __restrict__ out)
{
    const int b = blockIdx.x;
    const int t = threadIdx.x;

    __shared__ float s_rw[18];       // combined r-conv weights (c*9+ky*3+kx)
    __shared__ float s_rb;           // combined r bias
    __shared__ float s_flag;         // 0.0 iff w is all zeros
    __shared__ float s_qw[NA * 9];   // q_w  (a*9 + k)
    __shared__ float s_ww[NA * 9];   // w    (a*9 + k)
    __shared__ float s_fc[8 * NA];   // fc_w (j*10 + a)
    __shared__ float rs[IMS * IMS];      // r grid      (slow path only)
    __shared__ float vs[2][IMS * IMS];   // v dbl-buffer (slow path only)

    // ---- per-block prep (tiny; h_w/r_w reads hit L2 across blocks) ----
    if (t < 18) {
        float acc = 0.f;
        for (int h = 0; h < NH; ++h) acc += r_w[h] * h_w[h * 18 + t];
        s_rw[t] = acc;
    } else if (t == 18) {
        float acc = 0.f;
        for (int h = 0; h < NH; ++h) acc += r_w[h] * h_b[h];
        s_rb = acc;
    } else if (t == 19) {
        float f = 0.f;
        for (int i = 0; i < NA * 9; ++i) if (w[i] != 0.f) f = 1.f;
        s_flag = f;
    }
    for (int i = t; i < NA * 9; i += 256) { s_qw[i] = q_w[i]; s_ww[i] = w[i]; }
    for (int i = t; i < 8 * NA; i += 256) s_fc[i] = fc_w[i];
    __syncthreads();

    const float rb = s_rb;
    const bool  wzero = (s_flag == 0.f);   // uniform across grid
    const int   s1 = S1[b], s2 = S2[b];
    const float* Xb = X + (size_t)b * 2 * IMS * IMS;

    // r at (y,x); OOB -> 0 (zero padding for the downstream SAME q-conv)
    auto r_at = [&](int y, int x) -> float {
        if (y < 0 || y >= IMS || x < 0 || x >= IMS) return 0.f;
        float acc = rb;
        #pragma unroll
        for (int c = 0; c < 2; ++c)
            #pragma unroll
            for (int ky = 0; ky < 3; ++ky) {
                int yy = y + ky - 1;
                if (yy < 0 || yy >= IMS) continue;
                #pragma unroll
                for (int kx = 0; kx < 3; ++kx) {
                    int xx = x + kx - 1;
                    if (xx < 0 || xx >= IMS) continue;
                    acc += s_rw[c * 9 + ky * 3 + kx] * Xb[(c * IMS + yy) * IMS + xx];
                }
            }
        return acc;
    };

    // logits + softmax epilogue from q[10] (thread 0 only)
    auto epilogue = [&](const float* q) {
        float l[8], mx = -1e30f;
        #pragma unroll
        for (int j = 0; j < 8; ++j) {
            float acc = 0.f;
            #pragma unroll
            for (int a = 0; a < NA; ++a) acc += s_fc[j * NA + a] * q[a];
            l[j] = acc; mx = fmaxf(mx, acc);
        }
        float e[8], sum = 0.f;
        #pragma unroll
        for (int j = 0; j < 8; ++j) { e[j] = expf(l[j] - mx); sum += e[j]; }
        float inv = 1.f / sum;
        #pragma unroll
        for (int j = 0; j < 8; ++j) {
            out[b * 8 + j] = l[j];               // logits
            out[NB * 8 + b * 8 + j] = e[j] * inv; // probs
        }
    };

    if (wzero) {
        // ---- fast path: VI is a no-op; only a 3x3 r-patch is needed ----
        if (t == 0) {
            float rp[9];
            #pragma unroll
            for (int dy = 0; dy < 3; ++dy)
                #pragma unroll
                for (int dx = 0; dx < 3; ++dx)
                    rp[dy * 3 + dx] = r_at(s1 + dy - 1, s2 + dx - 1);
            float q[NA];
            #pragma unroll
            for (int a = 0; a < NA; ++a) {
                float acc = 0.f;
                #pragma unroll
                for (int k = 0; k < 9; ++k) acc += s_qw[a * 9 + k] * rp[k];
                q[a] = acc;
            }
            epilogue(q);
        }
        return;
    }

    // ---- general path: full value iteration on the 64x64 grid in LDS ----
    for (int cid = t; cid < IMS * IMS; cid += 256) {
        rs[cid] = r_at(cid >> 6, cid & 63);
    }
    __syncthreads();

    auto gather_nb = [&](const float* buf, int y, int x, float* nb) {
        #pragma unroll
        for (int ky = 0; ky < 3; ++ky)
            #pragma unroll
            for (int kx = 0; kx < 3; ++kx) {
                int yy = y + ky - 1, xx = x + kx - 1;
                nb[ky * 3 + kx] = (yy < 0 || yy >= IMS || xx < 0 || xx >= IMS)
                                      ? 0.f : buf[yy * IMS + xx];
            }
    };

    // v0 = max_a conv(r, q_w)
    for (int cid = t; cid < IMS * IMS; cid += 256) {
        int y = cid >> 6, x = cid & 63;
        float rn[9]; gather_nb(rs, y, x, rn);
        float vmax = -1e30f;
        #pragma unroll
        for (int a = 0; a < NA; ++a) {
            float acc = 0.f;
            #pragma unroll
            for (int k = 0; k < 9; ++k) acc += s_qw[a * 9 + k] * rn[k];
            vmax = fmaxf(vmax, acc);
        }
        vs[0][cid] = vmax;
    }
    __syncthreads();

    const int kk = *kptr;
    int cur = 0;
    for (int it = 1; it < kk; ++it) {
        for (int cid = t; cid < IMS * IMS; cid += 256) {
            int y = cid >> 6, x = cid & 63;
            float rn[9], vn[9];
            gather_nb(rs, y, x, rn);
            gather_nb(vs[cur], y, x, vn);
            float vmax = -1e30f;
            #pragma unroll
            for (int a = 0; a < NA; ++a) {
                float acc = 0.f;
                #pragma unroll
                for (int k = 0; k < 9; ++k)
                    acc += s_qw[a * 9 + k] * rn[k] + s_ww[a * 9 + k] * vn[k];
                vmax = fmaxf(vmax, acc);
            }
            vs[1 - cur][cid] = vmax;
        }
        __syncthreads();
        cur ^= 1;
    }

    if (t == 0) {
        float rn[9], vn[9];
        gather_nb(rs, s1, s2, rn);
        gather_nb(vs[cur], s1, s2, vn);
        float q[NA];
        #pragma unroll
        for (int a = 0; a < NA; ++a) {
            float acc = 0.f;
            #pragma unroll
            for (int k = 0; k < 9; ++k)
                acc += s_qw[a * 9 + k] * rn[k] + s_ww[a * 9 + k] * vn[k];
            q[a] = acc;
        }
        epilogue(q);
    }
}

extern "C" void kernel_launch(void* const* d_in, const int* in_sizes, int n_in,
                              void* d_out, int out_size, void* d_ws, size_t ws_size,
                              hipStream_t stream) {
    const float* X    = (const float*)d_in[0];
    const float* h_w  = (const float*)d_in[1];
    const float* h_b  = (const float*)d_in[2];
    const float* r_w  = (const float*)d_in[3];
    const float* q_w  = (const float*)d_in[4];
    const float* w    = (const float*)d_in[5];
    const float* fc_w = (const float*)d_in[6];
    const int*   S1   = (const int*)d_in[7];
    const int*   S2   = (const int*)d_in[8];
    // d_in[9]=O1, d_in[10]=O2 are unused by the reference
    const int*   kptr = (const int*)d_in[11];
    float* out = (float*)d_out;

    vin_all<<<dim3(NB), dim3(256), 0, stream>>>(
        X, h_w, h_b, r_w, q_w, w, fc_w, S1, S2, kptr, out);
}

// Round 2
// 86.945 us; speedup vs baseline: 1.1103x; 1.1103x over previous
//
#include <hip/hip_runtime.h>
#include <math.h>

// Problem constants (from reference): B=128, L_I=2, L_H=150, L_Q=10, IMSIZE=64, K=50
#define NB  128
#define IMS 64
#define NA  10
#define NH  150

// Algebra: r = conv1x1(conv(X,h_w)+h_b, r_w) collapses to a single (2,3,3) conv:
//   rw_comb[c,ky,kx] = sum_h r_w[h]*h_w[h,c,ky,kx],  rb = sum_h r_w[h]*h_b[h].
// Data fact (detected at RUNTIME, not assumed): w (the v-channel of w_cat) is all
// zeros -> q = conv(r, q_w) independent of v for every VI step, so only a 3x3
// r-patch around (S1,S2) is needed. w != 0 falls back to full in-LDS VI.
//
// R1->R2: the prep reductions were serial per-thread (150-iter global-load loops
// on 19 lanes of one wave, 9x r_at on thread 0) -> latency-bound. Now the 19
// dot products are spread over 190 threads (15 loads each), the w-scan over 90
// threads, and the 9 r-patch values over 9 threads.

__global__ __launch_bounds__(256) void vin_all(
    const float* __restrict__ X,
    const float* __restrict__ h_w,
    const float* __restrict__ h_b,
    const float* __restrict__ r_w,
    const float* __restrict__ q_w,
    const float* __restrict__ w,
    const float* __restrict__ fc_w,
    const int*   __restrict__ S1,
    const int*   __restrict__ S2,
    const int*   __restrict__ kptr,
    float*       __restrict__ out)
{
    const int b = blockIdx.x;
    const int t = threadIdx.x;

    __shared__ float s_part[190];    // partial sums for the 19 combined weights
    __shared__ float s_rw[18];       // combined r-conv weights (c*9+ky*3+kx)
    __shared__ float s_rb;           // combined r bias
    __shared__ int   s_if;           // 1 iff w has any nonzero
    __shared__ float s_qw[NA * 9];   // q_w  (a*9 + k)
    __shared__ float s_ww[NA * 9];   // w    (a*9 + k)
    __shared__ float s_fc[8 * NA];   // fc_w (j*10 + a)
    __shared__ float s_rp[9];        // 3x3 r patch (fast path)
    __shared__ float rs[IMS * IMS];      // r grid      (slow path only)
    __shared__ float vs[2][IMS * IMS];   // v dbl-buffer (slow path only)

    if (t == 0) s_if = 0;
    __syncthreads();

    // ---- parallel prep: 19 dot-products of length 150, spread 10-wide ----
    if (t < 190) {
        const int o = t / 10, j = t % 10;
        float acc = 0.f;
        if (o < 18) {
            for (int h = j; h < NH; h += 10) acc += r_w[h] * h_w[h * 18 + o];
        } else {
            for (int h = j; h < NH; h += 10) acc += r_w[h] * h_b[h];
        }
        s_part[t] = acc;
    }
    if (t < NA * 9) {
        float wv = w[t];
        s_qw[t] = q_w[t];
        s_ww[t] = wv;
        if (wv != 0.f) s_if = 1;     // benign race: all writers store 1
    }
    if (t >= 128 && t < 128 + 8 * NA) s_fc[t - 128] = fc_w[t - 128];
    __syncthreads();

    if (t < 19) {
        float acc = 0.f;
        #pragma unroll
        for (int j = 0; j < 10; ++j) acc += s_part[t * 10 + j];
        if (t < 18) s_rw[t] = acc; else s_rb = acc;
    }
    __syncthreads();

    const float rb   = s_rb;
    const bool wzero = (s_if == 0);  // uniform across grid
    const int  s1 = S1[b], s2 = S2[b];
    const float* Xb = X + (size_t)b * 2 * IMS * IMS;

    // r at (y,x); OOB -> 0 (zero padding for the downstream SAME q-conv)
    auto r_at = [&](int y, int x) -> float {
        if (y < 0 || y >= IMS || x < 0 || x >= IMS) return 0.f;
        float acc = rb;
        #pragma unroll
        for (int c = 0; c < 2; ++c)
            #pragma unroll
            for (int ky = 0; ky < 3; ++ky) {
                int yy = y + ky - 1;
                if (yy < 0 || yy >= IMS) continue;
                #pragma unroll
                for (int kx = 0; kx < 3; ++kx) {
                    int xx = x + kx - 1;
                    if (xx < 0 || xx >= IMS) continue;
                    acc += s_rw[c * 9 + ky * 3 + kx] * Xb[(c * IMS + yy) * IMS + xx];
                }
            }
        return acc;
    };

    // logits + softmax epilogue from q[10] (single thread)
    auto epilogue = [&](const float* q) {
        float l[8], mx = -1e30f;
        #pragma unroll
        for (int j = 0; j < 8; ++j) {
            float acc = 0.f;
            #pragma unroll
            for (int a = 0; a < NA; ++a) acc += s_fc[j * NA + a] * q[a];
            l[j] = acc; mx = fmaxf(mx, acc);
        }
        float e[8], sum = 0.f;
        #pragma unroll
        for (int j = 0; j < 8; ++j) { e[j] = expf(l[j] - mx); sum += e[j]; }
        float inv = 1.f / sum;
        #pragma unroll
        for (int j = 0; j < 8; ++j) {
            out[b * 8 + j] = l[j];                // logits
            out[NB * 8 + b * 8 + j] = e[j] * inv; // probs
        }
    };

    if (wzero) {
        // ---- fast path: VI is a no-op; only a 3x3 r-patch is needed ----
        if (t < 9) {
            const int dy = t / 3, dx = t % 3;
            s_rp[t] = r_at(s1 + dy - 1, s2 + dx - 1);
        }
        __syncthreads();
        if (t == 0) {
            float q[NA];
            #pragma unroll
            for (int a = 0; a < NA; ++a) {
                float acc = 0.f;
                #pragma unroll
                for (int k = 0; k < 9; ++k) acc += s_qw[a * 9 + k] * s_rp[k];
                q[a] = acc;
            }
            epilogue(q);
        }
        return;
    }

    // ---- general path: full value iteration on the 64x64 grid in LDS ----
    for (int cid = t; cid < IMS * IMS; cid += 256) {
        rs[cid] = r_at(cid >> 6, cid & 63);
    }
    __syncthreads();

    auto gather_nb = [&](const float* buf, int y, int x, float* nb) {
        #pragma unroll
        for (int ky = 0; ky < 3; ++ky)
            #pragma unroll
            for (int kx = 0; kx < 3; ++kx) {
                int yy = y + ky - 1, xx = x + kx - 1;
                nb[ky * 3 + kx] = (yy < 0 || yy >= IMS || xx < 0 || xx >= IMS)
                                      ? 0.f : buf[yy * IMS + xx];
            }
    };

    // v0 = max_a conv(r, q_w)
    for (int cid = t; cid < IMS * IMS; cid += 256) {
        int y = cid >> 6, x = cid & 63;
        float rn[9]; gather_nb(rs, y, x, rn);
        float vmax = -1e30f;
        #pragma unroll
        for (int a = 0; a < NA; ++a) {
            float acc = 0.f;
            #pragma unroll
            for (int k = 0; k < 9; ++k) acc += s_qw[a * 9 + k] * rn[k];
            vmax = fmaxf(vmax, acc);
        }
        vs[0][cid] = vmax;
    }
    __syncthreads();

    const int kk = *kptr;
    int cur = 0;
    for (int it = 1; it < kk; ++it) {
        for (int cid = t; cid < IMS * IMS; cid += 256) {
            int y = cid >> 6, x = cid & 63;
            float rn[9], vn[9];
            gather_nb(rs, y, x, rn);
            gather_nb(vs[cur], y, x, vn);
            float vmax = -1e30f;
            #pragma unroll
            for (int a = 0; a < NA; ++a) {
                float acc = 0.f;
                #pragma unroll
                for (int k = 0; k < 9; ++k)
                    acc += s_qw[a * 9 + k] * rn[k] + s_ww[a * 9 + k] * vn[k];
                vmax = fmaxf(vmax, acc);
            }
            vs[1 - cur][cid] = vmax;
        }
        __syncthreads();
        cur ^= 1;
    }

    if (t == 0) {
        float rn[9], vn[9];
        gather_nb(rs, s1, s2, rn);
        gather_nb(vs[cur], s1, s2, vn);
        float q[NA];
        #pragma unroll
        for (int a = 0; a < NA; ++a) {
            float acc = 0.f;
            #pragma unroll
            for (int k = 0; k < 9; ++k)
                acc += s_qw[a * 9 + k] * rn[k] + s_ww[a * 9 + k] * vn[k];
            q[a] = acc;
        }
        epilogue(q);
    }
}

extern "C" void kernel_launch(void* const* d_in, const int* in_sizes, int n_in,
                              void* d_out, int out_size, void* d_ws, size_t ws_size,
                              hipStream_t stream) {
    const float* X    = (const float*)d_in[0];
    const float* h_w  = (const float*)d_in[1];
    const float* h_b  = (const float*)d_in[2];
    const float* r_w  = (const float*)d_in[3];
    const float* q_w  = (const float*)d_in[4];
    const float* w    = (const float*)d_in[5];
    const float* fc_w = (const float*)d_in[6];
    const int*   S1   = (const int*)d_in[7];
    const int*   S2   = (const int*)d_in[8];
    // d_in[9]=O1, d_in[10]=O2 unused by the reference
    const int*   kptr = (const int*)d_in[11];
    float* out = (float*)d_out;

    vin_all<<<dim3(NB), dim3(256), 0, stream>>>(
        X, h_w, h_b, r_w, q_w, w, fc_w, S1, S2, kptr, out);
}

// Round 3
// 83.860 us; speedup vs baseline: 1.1512x; 1.0368x over previous
//
#include <hip/hip_runtime.h>
#include <math.h>

// Problem constants (from reference): B=128, L_I=2, L_H=150, L_Q=10, IMSIZE=64, K=50
#define NB  128
#define IMS 64
#define NA  10
#define NH  150

// Algebra: r = conv1x1(conv(X,h_w)+h_b, r_w) collapses to a single (2,3,3) conv:
//   rw_comb[c,ky,kx] = sum_h r_w[h]*h_w[h,c,ky,kx],  rb = sum_h r_w[h]*h_b[h].
// Data fact (detected at RUNTIME, not assumed): w (the v-channel of w_cat) is all
// zeros -> q = conv(r, q_w) independent of v for every VI step, so only a 3x3
// r-patch around (S1,S2) is needed. w != 0 falls back to full in-LDS VI.
//
// R2->R3 (latency-round minimization): all global traffic is now one parallel
// round per phase — r_w staged to LDS once (150 lanes), the 5x5x2 X patch loaded
// by 50 lanes of wave 3 (overlapped with the 190-lane h_w dot products), and the
// fast-path arithmetic runs out of LDS in small parallel stages (9-lane r patch,
// 10-lane q, 8-lane logits, 1-lane softmax). No lane issues chained scattered
// global loads anymore.

__global__ __launch_bounds__(256) void vin_all(
    const float* __restrict__ X,
    const float* __restrict__ h_w,
    const float* __restrict__ h_b,
    const float* __restrict__ r_w,
    const float* __restrict__ q_w,
    const float* __restrict__ w,
    const float* __restrict__ fc_w,
    const int*   __restrict__ S1,
    const int*   __restrict__ S2,
    const int*   __restrict__ kptr,
    float*       __restrict__ out)
{
    const int b = blockIdx.x;
    const int t = threadIdx.x;

    __shared__ float s_rwin[NH];     // r_w staged in LDS
    __shared__ float s_part[190];    // partial sums for the 19 combined weights
    __shared__ float s_rw[18];       // combined r-conv weights (c*9+ky*3+kx)
    __shared__ float s_rb;           // combined r bias
    __shared__ int   s_if;           // 1 iff w has any nonzero
    __shared__ int   s_s1, s_s2;     // gather coords for this batch
    __shared__ float s_qw[NA * 9];   // q_w  (a*9 + k)
    __shared__ float s_ww[NA * 9];   // w    (a*9 + k)
    __shared__ float s_fc[8 * NA];   // fc_w (j*10 + a)
    __shared__ float s_xp[2][5][5];  // 5x5 X patch, OOB pre-zeroed (fast path)
    __shared__ float s_rp[9];        // 3x3 r patch (fast path)
    __shared__ float s_q[NA];        // q at gather cell (fast path)
    __shared__ float s_l[8];         // logits (fast path)
    __shared__ float rs[IMS * IMS];      // r grid      (slow path only)
    __shared__ float vs[2][IMS * IMS];   // v dbl-buffer (slow path only)

    const float* Xb = X + (size_t)b * 2 * IMS * IMS;

    // ---- phase 0: one parallel round of small-table loads ----
    if (t < NH)     s_rwin[t] = r_w[t];
    if (t < NA * 9) { s_qw[t] = q_w[t]; s_ww[t] = w[t]; }
    if (t < 8 * NA) s_fc[t] = fc_w[t];
    if (t == 252)   s_if = 0;
    if (t == 253)   s_s1 = (int)S1[b];
    if (t == 254)   s_s2 = (int)S2[b];
    __syncthreads();

    // ---- phase 1: h_w dot products (waves 0-2) + X patch (wave 3) ----
    if (t < 190) {
        const int o = t / 10, j = t % 10;
        float acc = 0.f;
        if (o < 18) {
            for (int h = j; h < NH; h += 10) acc += s_rwin[h] * h_w[h * 18 + o];
        } else {
            for (int h = j; h < NH; h += 10) acc += s_rwin[h] * h_b[h];
        }
        s_part[t] = acc;
    } else if (t >= 192 && t < 242) {
        const int u = t - 192, c = u / 25, p = u % 25, py = p / 5, px = p % 5;
        const int y = s_s1 - 2 + py, x = s_s2 - 2 + px;
        s_xp[c][py][px] = (y < 0 || y >= IMS || x < 0 || x >= IMS)
                              ? 0.f : Xb[(c * IMS + y) * IMS + x];
    } else if (t >= 242) {
        for (int i = t - 242; i < NA * 9; i += 14)
            if (s_ww[i] != 0.f) s_if = 1;   // benign race: all writers store 1
    }
    __syncthreads();

    // ---- phase 2: reduce the 19 partials ----
    if (t < 19) {
        float acc = 0.f;
        #pragma unroll
        for (int j = 0; j < 10; ++j) acc += s_part[t * 10 + j];
        if (t < 18) s_rw[t] = acc; else s_rb = acc;
    }
    __syncthreads();

    const float rb   = s_rb;
    const bool wzero = (s_if == 0);  // uniform across grid
    const int  s1 = s_s1, s2 = s_s2;

    if (wzero) {
        // ---- fast path: VI is a no-op; everything from LDS, staged parallel ----
        if (t < 9) {
            const int dy = t / 3, dx = t % 3;
            const int y = s1 + dy - 1, x = s2 + dx - 1;
            float acc = 0.f;
            if (!(y < 0 || y >= IMS || x < 0 || x >= IMS)) {
                acc = rb;
                #pragma unroll
                for (int c = 0; c < 2; ++c)
                    #pragma unroll
                    for (int ky = 0; ky < 3; ++ky)
                        #pragma unroll
                        for (int kx = 0; kx < 3; ++kx)
                            acc += s_rw[c * 9 + ky * 3 + kx] * s_xp[c][dy + ky][dx + kx];
            }
            s_rp[t] = acc;
        }
        __syncthreads();
        if (t < NA) {
            float acc = 0.f;
            #pragma unroll
            for (int k = 0; k < 9; ++k) acc += s_qw[t * 9 + k] * s_rp[k];
            s_q[t] = acc;
        }
        __syncthreads();
        if (t < 8) {
            float acc = 0.f;
            #pragma unroll
            for (int a = 0; a < NA; ++a) acc += s_fc[t * NA + a] * s_q[a];
            s_l[t] = acc;
            out[b * 8 + t] = acc;              // logits stored immediately
        }
        __syncthreads();
        if (t == 0) {
            float mx = s_l[0];
            #pragma unroll
            for (int j = 1; j < 8; ++j) mx = fmaxf(mx, s_l[j]);
            float e[8], sum = 0.f;
            #pragma unroll
            for (int j = 0; j < 8; ++j) { e[j] = expf(s_l[j] - mx); sum += e[j]; }
            const float inv = 1.f / sum;
            #pragma unroll
            for (int j = 0; j < 8; ++j)
                out[NB * 8 + b * 8 + j] = e[j] * inv;  // probs
        }
        return;
    }

    // ---- general path: full value iteration on the 64x64 grid in LDS ----
    // r at (y,x) from global X; OOB -> 0
    auto r_at = [&](int y, int x) -> float {
        if (y < 0 || y >= IMS || x < 0 || x >= IMS) return 0.f;
        float acc = rb;
        #pragma unroll
        for (int c = 0; c < 2; ++c)
            #pragma unroll
            for (int ky = 0; ky < 3; ++ky) {
                int yy = y + ky - 1;
                if (yy < 0 || yy >= IMS) continue;
                #pragma unroll
                for (int kx = 0; kx < 3; ++kx) {
                    int xx = x + kx - 1;
                    if (xx < 0 || xx >= IMS) continue;
                    acc += s_rw[c * 9 + ky * 3 + kx] * Xb[(c * IMS + yy) * IMS + xx];
                }
            }
        return acc;
    };

    for (int cid = t; cid < IMS * IMS; cid += 256) {
        rs[cid] = r_at(cid >> 6, cid & 63);
    }
    __syncthreads();

    auto gather_nb = [&](const float* buf, int y, int x, float* nb) {
        #pragma unroll
        for (int ky = 0; ky < 3; ++ky)
            #pragma unroll
            for (int kx = 0; kx < 3; ++kx) {
                int yy = y + ky - 1, xx = x + kx - 1;
                nb[ky * 3 + kx] = (yy < 0 || yy >= IMS || xx < 0 || xx >= IMS)
                                      ? 0.f : buf[yy * IMS + xx];
            }
    };

    // v0 = max_a conv(r, q_w)
    for (int cid = t; cid < IMS * IMS; cid += 256) {
        int y = cid >> 6, x = cid & 63;
        float rn[9]; gather_nb(rs, y, x, rn);
        float vmax = -1e30f;
        #pragma unroll
        for (int a = 0; a < NA; ++a) {
            float acc = 0.f;
            #pragma unroll
            for (int k = 0; k < 9; ++k) acc += s_qw[a * 9 + k] * rn[k];
            vmax = fmaxf(vmax, acc);
        }
        vs[0][cid] = vmax;
    }
    __syncthreads();

    const int kk = *kptr;
    int cur = 0;
    for (int it = 1; it < kk; ++it) {
        for (int cid = t; cid < IMS * IMS; cid += 256) {
            int y = cid >> 6, x = cid & 63;
            float rn[9], vn[9];
            gather_nb(rs, y, x, rn);
            gather_nb(vs[cur], y, x, vn);
            float vmax = -1e30f;
            #pragma unroll
            for (int a = 0; a < NA; ++a) {
                float acc = 0.f;
                #pragma unroll
                for (int k = 0; k < 9; ++k)
                    acc += s_qw[a * 9 + k] * rn[k] + s_ww[a * 9 + k] * vn[k];
                vmax = fmaxf(vmax, acc);
            }
            vs[1 - cur][cid] = vmax;
        }
        __syncthreads();
        cur ^= 1;
    }

    if (t == 0) {
        float rn[9], vn[9];
        gather_nb(rs, s1, s2, rn);
        gather_nb(vs[cur], s1, s2, vn);
        float q[NA];
        #pragma unroll
        for (int a = 0; a < NA; ++a) {
            float acc = 0.f;
            #pragma unroll
            for (int k = 0; k < 9; ++k)
                acc += s_qw[a * 9 + k] * rn[k] + s_ww[a * 9 + k] * vn[k];
            q[a] = acc;
        }
        float l[8], mx = -1e30f;
        #pragma unroll
        for (int j = 0; j < 8; ++j) {
            float acc = 0.f;
            #pragma unroll
            for (int a = 0; a < NA; ++a) acc += s_fc[j * NA + a] * q[a];
            l[j] = acc; mx = fmaxf(mx, acc);
        }
        float e[8], sum = 0.f;
        #pragma unroll
        for (int j = 0; j < 8; ++j) { e[j] = expf(l[j] - mx); sum += e[j]; }
        const float inv = 1.f / sum;
        #pragma unroll
        for (int j = 0; j < 8; ++j) {
            out[b * 8 + j] = l[j];
            out[NB * 8 + b * 8 + j] = e[j] * inv;
        }
    }
}

extern "C" void kernel_launch(void* const* d_in, const int* in_sizes, int n_in,
                              void* d_out, int out_size, void* d_ws, size_t ws_size,
                              hipStream_t stream) {
    const float* X    = (const float*)d_in[0];
    const float* h_w  = (const float*)d_in[1];
    const float* h_b  = (const float*)d_in[2];
    const float* r_w  = (const float*)d_in[3];
    const float* q_w  = (const float*)d_in[4];
    const float* w    = (const float*)d_in[5];
    const float* fc_w = (const float*)d_in[6];
    const int*   S1   = (const int*)d_in[7];
    const int*   S2   = (const int*)d_in[8];
    // d_in[9]=O1, d_in[10]=O2 unused by the reference
    const int*   kptr = (const int*)d_in[11];
    float* out = (float*)d_out;

    vin_all<<<dim3(NB), dim3(256), 0, stream>>>(
        X, h_w, h_b, r_w, q_w, w, fc_w, S1, S2, kptr, out);
}